// Round 3
// baseline (97695.288 us; speedup 1.0000x reference)
//
#include <hip/hip_runtime.h>
#include <math.h>

#define T_DIM 512
#define B_DIM 64
#define I_DIM 1024
#define H_DIM 1024

// d_out layout (flat f32): ys [T][B][2H], hT_f [B][H], cT_f, hT_b, cT_b
#define OUT_HTF (T_DIM * B_DIM * 2 * H_DIM)
#define OUT_CTF (OUT_HTF + B_DIM * H_DIM)
#define OUT_HTB (OUT_CTF + B_DIM * H_DIM)
#define OUT_CTB (OUT_HTB + B_DIM * H_DIM)

__device__ __forceinline__ float sigmoidf_(float v) {
    return 1.0f / (1.0f + expf(-v));
}

// One time step, both directions, fused x+h GEMM (K=2048).
// Grid: 256 blocks = dir(2) x 128 unit-slices. Block: 256 threads = 4 waves.
// Mapping: lane (tid&63) = batch row m; wave (tid>>6) = gate g; each thread
// computes 8 gate columns (units u0..u0+7) for its row -> j_t=8:
//   - W rows are wave-uniform -> W loads broadcast (one L1 line per load)
//   - LDS A-read cycles = 0.75x FMA cycles -> FMA-bound
// LDS: 2 x [64 rows][128 k] f32 double-buffered = 64 KB, XOR-swizzled for the
// lane=m column read (q' = q ^ (m&31): 2-way aliasing = conflict-free).
__global__ __launch_bounds__(256, 1) void lstm_step_fused(
    const float* __restrict__ x,
    const float* __restrict__ h0f, const float* __restrict__ c0f,
    const float* __restrict__ h0b, const float* __restrict__ c0b,
    const float* __restrict__ wihf, const float* __restrict__ whhf,
    const float* __restrict__ bihf, const float* __restrict__ bhhf,
    const float* __restrict__ wihb, const float* __restrict__ whhb,
    const float* __restrict__ bihb, const float* __restrict__ bhhb,
    float* __restrict__ out, int step)
{
    __shared__ float smem[2 * 64 * 128];   // 64 KB

    const int tid  = threadIdx.x;
    const int bid  = blockIdx.x;
    const int dir  = bid >> 7;             // 0 fwd, 1 bwd
    const int u0   = (bid & 127) * 8;      // unit slice
    const int t    = dir ? (T_DIM - 1 - step) : step;
    const int lane = tid & 63;             // batch row m
    const int g    = tid >> 6;             // gate 0..3 (i,f,g,o)

    const float* w_ih = dir ? wihb : wihf;
    const float* w_hh = dir ? whhb : whhf;
    const float* bih  = dir ? bihb : bihf;
    const float* bhh  = dir ? bhhb : bhhf;
    const float* xt   = x + (size_t)t * B_DIM * I_DIM;

    const float* hprev;
    int hst;
    if (step == 0) {
        hprev = dir ? h0b : h0f;
        hst = H_DIM;
    } else {
        const int tprev = dir ? (t + 1) : (t - 1);
        hprev = out + (size_t)tprev * B_DIM * 2 * H_DIM + dir * H_DIM;
        hst = 2 * H_DIM;
    }

    const int row0 = g * H_DIM + u0;       // first of this thread's 8 W rows

    // acc init = bias (b_ih + b_hh), per column
    float acc[8];
#pragma unroll
    for (int ci = 0; ci < 8; ++ci) acc[ci] = bih[row0 + ci] + bhh[row0 + ci];

    float4 ld[8];                          // staging regs for next chunk

    auto issue_loads = [&](int kc) {
        const bool isX = (kc < 8);
        const float* src = isX ? xt : hprev;
        const int stride = isX ? I_DIM : hst;
        const int kb = (kc & 7) * 128;
#pragma unroll
        for (int p = 0; p < 8; ++p) {
            const int e = p * 256 + tid;   // 0..2047
            const int m = e >> 5;          // row 0..63
            const int q = e & 31;          // float4 col 0..31
            ld[p] = *reinterpret_cast<const float4*>(
                src + (size_t)m * stride + kb + q * 4);
        }
    };

    auto write_smem = [&](int buf) {
        float* dst = smem + buf * 8192;
#pragma unroll
        for (int p = 0; p < 8; ++p) {
            const int e = p * 256 + tid;
            const int m = e >> 5;
            const int q = e & 31;
            const int qs = q ^ (m & 31);   // swizzle for lane=m column reads
            *reinterpret_cast<float4*>(&dst[m * 128 + qs * 4]) = ld[p];
        }
    };

    auto compute = [&](int kc, int buf) {
        const bool isX = (kc < 8);
        const int kb = (kc & 7) * 128;
        // wave-uniform W base for this chunk: 8 rows of 1024, window [kb, kb+128)
        const float* wb = (isX ? w_ih : w_hh) + (size_t)row0 * 1024 + kb;
        const float* sb = smem + buf * 8192 + lane * 128;
        const int msw = lane & 31;
#pragma unroll 4
        for (int q = 0; q < 32; ++q) {
            const float4 a = *reinterpret_cast<const float4*>(&sb[(q ^ msw) * 4]);
#pragma unroll
            for (int ci = 0; ci < 8; ++ci) {
                const float4 wv =
                    *reinterpret_cast<const float4*>(wb + (size_t)ci * 1024 + q * 4);
                acc[ci] = fmaf(a.x, wv.x, fmaf(a.y, wv.y,
                          fmaf(a.z, wv.z, fmaf(a.w, wv.w, acc[ci]))));
            }
        }
    };

    // ---- K loop: 16 chunks of 128 (8 x-chunks, then 8 h-chunks) ----
    issue_loads(0);
    write_smem(0);
    __syncthreads();
    for (int kc = 0; kc < 16; ++kc) {
        if (kc < 15) issue_loads(kc + 1);
        compute(kc, kc & 1);
        __syncthreads();
        if (kc < 15) {
            write_smem((kc + 1) & 1);
            __syncthreads();
        }
    }

    // ---- gate exchange: sm[g][u 0..7][m 0..63] = 8 KB (reuse smem) ----
#pragma unroll
    for (int ci = 0; ci < 8; ++ci)
        smem[g * 512 + ci * 64 + lane] = acc[ci];
    __syncthreads();

    // ---- cell update: 512 cells (64 m x 8 u), 2 per thread ----
    float* cslot = out + (dir ? OUT_CTB : OUT_CTF);
    float* hslot = out + (dir ? OUT_HTB : OUT_HTF);
    const float* cinit = dir ? c0b : c0f;
#pragma unroll
    for (int s2 = 0; s2 < 2; ++s2) {
        const int idx = s2 * 256 + tid;    // 0..511
        const int u = idx & 7;             // unit offset (lanes: 8 m x 8 u)
        const int m = idx >> 3;            // batch row
        const int uu = u0 + u;

        const float ig = smem[0 * 512 + u * 64 + m];
        const float fg = smem[1 * 512 + u * 64 + m];
        const float gg = smem[2 * 512 + u * 64 + m];
        const float og = smem[3 * 512 + u * 64 + m];

        const float cp = (step == 0) ? cinit[m * H_DIM + uu]
                                     : cslot[m * H_DIM + uu];
        const float cn = sigmoidf_(fg) * cp + sigmoidf_(ig) * tanhf(gg);
        const float h  = sigmoidf_(og) * tanhf(cn);
        cslot[m * H_DIM + uu] = cn;
        out[(size_t)t * B_DIM * 2 * H_DIM + m * 2 * H_DIM + dir * H_DIM + uu] = h;
        if (step == T_DIM - 1) hslot[m * H_DIM + uu] = h;
    }
}

extern "C" void kernel_launch(void* const* d_in, const int* in_sizes, int n_in,
                              void* d_out, int out_size, void* d_ws, size_t ws_size,
                              hipStream_t stream)
{
    const float* x    = (const float*)d_in[0];
    const float* h0f  = (const float*)d_in[1];
    const float* c0f  = (const float*)d_in[2];
    const float* h0b  = (const float*)d_in[3];
    const float* c0b  = (const float*)d_in[4];
    const float* wihf = (const float*)d_in[5];
    const float* whhf = (const float*)d_in[6];
    const float* bihf = (const float*)d_in[7];
    const float* bhhf = (const float*)d_in[8];
    const float* wihb = (const float*)d_in[9];
    const float* whhb = (const float*)d_in[10];
    const float* bihb = (const float*)d_in[11];
    const float* bhhb = (const float*)d_in[12];
    float* out = (float*)d_out;

    for (int s = 0; s < T_DIM; ++s) {
        lstm_step_fused<<<dim3(256), dim3(256), 0, stream>>>(
            x, h0f, c0f, h0b, c0b,
            wihf, whhf, bihf, bhhf,
            wihb, whhb, bihb, bhhb,
            out, s);
    }
}